// Round 3
// baseline (405.086 us; speedup 1.0000x reference)
//
#include <hip/hip_runtime.h>
#include <cstdint>

// LSTM cell with (diagonal) peephole connections.
//   K1: cast x|hx -> bf16 A [4096][2048]; cast Wih|Whh -> bf16 W' [4096][2048]
//       with gate-interleaved row permutation np = (h>>4)*64 + g*16 + (h&15).
//   K2: 256x256 bf16 MFMA GEMM, 512 thr = 8 waves (2M x 4N), wave tile
//       128Mx64N acc[8][4], BK=64, double-buffered 128 KiB LDS.
//   Round-3 schedule: PIPELINED ds_reads with COUNTED lgkmcnt, 2 barriers/tile
//   (was 9). Rounds 1-2 measured MfmaUtil pinned at 33%: per-phase
//   {reads; barrier; lgkm(0); MFMA; barrier} exposes read RETURNS (waves sit
//   at lgkm(0), matrix pipe idle) then runs MFMA with LDS pipe idle --
//   serial sum 2100+2060+barriers = measured 6300 cyc/tile. New schedule
//   overlaps the two pipes: reads for phase q+1 issued BEFORE MFMA(q), MFMA
//   waits only on its own operands via counted lgkm (DS retires in order):
//     issue A01 (8rd); lgkm(4); MFMA0 | issue A2; lgkm(4); MFMA1
//     | issue A3; lgkm(4); MFMA2 | lgkm(0); BARRIER(1)
//     | stage kt+2 -> buf[cur]; vmcnt(8) | BARRIER(2)
//     | issue B(kt+1) from buf[cur^1]; MFMA3
//   Safety: stage writes buf[cur] only after barrier(1) (every wave's lgkm(0)
//   = all its reads of buf[cur], incl. prev-tile B-prefetch, complete).
//   B(kt+1) reads issued after barrier(2): kt+1's gloads retired by vmcnt(8)
//   in every wave; kt+3's (next writers of buf[cur^1]) not yet issued.
//   Counted vmcnt(8) leaves kt+2's 8 loads in flight across both barriers
//   (never vmcnt(0) mid-loop). XCD-bijective remap (FETCH 83->59MB, keep).
//   XOR swizzle chunk' = chunk ^ (row&7) on global source of global_load_lds
//   and on LDS reads: 0 bank conflicts (measured). ds_reads are inline asm
//   (invisible to alias analysis; ordering ours via barriers + counted lgkm +
//   sched_barrier(0), rule #18). Fused LSTM epilogue, lane-local.

namespace {

constexpr int H   = 1024;   // hidden
constexpr int K2  = 2048;   // I + H
constexpr int BSZ = 4096;   // batch (M)
constexpr size_t OUT_CY = (size_t)BSZ * H;

typedef __attribute__((ext_vector_type(8))) short bf16x8;
typedef __attribute__((ext_vector_type(4))) float f32x4;
typedef __attribute__((ext_vector_type(8))) unsigned short u16x8;

__device__ __forceinline__ unsigned short f2bf(float f) {
  union { float f; uint32_t u; } v; v.f = f;
  uint32_t u = v.u;
  u += 0x7FFFu + ((u >> 16) & 1u);   // round-to-nearest-even
  return (unsigned short)(u >> 16);
}

__device__ __forceinline__ float sigm(float x) {
  return 1.0f / (1.0f + __expf(-x));
}
__device__ __forceinline__ float tanh_fast(float x) {
  return 1.0f - 2.0f / (1.0f + __expf(2.0f * x));
}

__device__ __forceinline__ void gload_lds16(const void* g, void* l) {
  __builtin_amdgcn_global_load_lds(
      (const __attribute__((address_space(1))) void*)g,
      (__attribute__((address_space(3))) void*)l, 16, 0, 0);
}

// raw ds_read_b128 at LDS byte address; no memory operand -> no compiler
// aliasing ties to global_load_lds destinations. Ordering is explicit.
__device__ __forceinline__ bf16x8 dsr_b128(unsigned addr) {
  bf16x8 r;
  asm volatile("ds_read_b128 %0, %1" : "=v"(r) : "v"(addr));
  return r;
}

}  // namespace

// ---- K1: both casts in one launch -------------------------------------------
__global__ __launch_bounds__(256) void cast_kernel(
    const float* __restrict__ x, const float* __restrict__ hx,
    const float* __restrict__ wih, const float* __restrict__ whh,
    unsigned short* __restrict__ A, unsigned short* __restrict__ W) {
  int b = blockIdx.x;
  bool isW = b >= 4096;
  int t = (isW ? b - 4096 : b) * 256 + threadIdx.x;
  int idx = t * 8;
  int n = idx >> 11;
  int k = idx & 2047;
  const float* s0 = isW ? wih : x;
  const float* s1 = isW ? whh : hx;
  const float* src = (k < H) ? (s0 + (size_t)n * H + k)
                             : (s1 + (size_t)n * H + (k - H));
  float4 v0 = *(const float4*)src;
  float4 v1 = *(const float4*)(src + 4);
  u16x8 o;
  o[0] = f2bf(v0.x); o[1] = f2bf(v0.y); o[2] = f2bf(v0.z); o[3] = f2bf(v0.w);
  o[4] = f2bf(v1.x); o[5] = f2bf(v1.y); o[6] = f2bf(v1.z); o[7] = f2bf(v1.w);
  if (isW) {
    int g = n >> 10, hh = n & 1023;
    int np = ((hh >> 4) << 6) + (g << 4) + (hh & 15);   // 64-wide gate groups
    *(u16x8*)(W + (size_t)np * K2 + k) = o;
  } else {
    *(u16x8*)(A + (size_t)idx) = o;
  }
}

// macros used inside the tile body (static indices everywhere, rule #20)
#define RD_A(AF, Q, BO)                                          \
  AF[0][0] = dsr_b128(abase + (BO) + (2 * (Q) + 0) * 2048 + kch0); \
  AF[0][1] = dsr_b128(abase + (BO) + (2 * (Q) + 0) * 2048 + kch1); \
  AF[1][0] = dsr_b128(abase + (BO) + (2 * (Q) + 1) * 2048 + kch0); \
  AF[1][1] = dsr_b128(abase + (BO) + (2 * (Q) + 1) * 2048 + kch1);

#define MFMA_PH(Q, AF, BC)                                                   \
  __builtin_amdgcn_s_setprio(1);                                             \
  _Pragma("unroll") for (int i2 = 0; i2 < 2; ++i2)                           \
      _Pragma("unroll") for (int j = 0; j < 4; ++j)                          \
          acc[2 * (Q) + i2][j] = __builtin_amdgcn_mfma_f32_16x16x32_bf16(    \
              AF[i2][0], BC[j][0], acc[2 * (Q) + i2][j], 0, 0, 0);           \
  _Pragma("unroll") for (int i2 = 0; i2 < 2; ++i2)                           \
      _Pragma("unroll") for (int j = 0; j < 4; ++j)                          \
          acc[2 * (Q) + i2][j] = __builtin_amdgcn_mfma_f32_16x16x32_bf16(    \
              AF[i2][1], BC[j][1], acc[2 * (Q) + i2][j], 0, 0, 0);           \
  __builtin_amdgcn_s_setprio(0);

#define LGKM(N)                                          \
  asm volatile("s_waitcnt lgkmcnt(" #N ")" ::: "memory"); \
  __builtin_amdgcn_sched_barrier(0);

// ---- K2: fused GEMM + LSTM epilogue -----------------------------------------
// grid = 256 blocks (16x16 logical), block = 512 (8 waves, 2M x 4N)
__global__ __launch_bounds__(512, 2) void lstm_fused_gemm(
    const unsigned short* __restrict__ A,   // [4096][2048] bf16
    const unsigned short* __restrict__ W,   // [4096][2048] bf16, permuted rows
    const float* __restrict__ cx,
    const float* __restrict__ bias_ih, const float* __restrict__ bias_hh,
    const float* __restrict__ Wpi, const float* __restrict__ Wpf,
    float* __restrict__ out) {
  // [buf][ A 256x64 | B 256x64 ] bf16 = 2 * 32768 shorts = 128 KiB
  __shared__ __align__(16) unsigned short lds[2 * 32768];

  const int tid  = threadIdx.x;
  const int lane = tid & 63;
  const int wave = tid >> 6;
  const int wm   = wave >> 2;          // 0..1: M half
  const int wn   = wave & 3;           // 0..3: N quarter

  // XCD-aware bijective remap: linear id b -> XCD b&7 -> 4bx x 8by patch.
  const int b   = blockIdx.y * 16 + blockIdx.x;
  const int xcd = b & 7, bidx = b >> 3;
  const int bx  = (xcd & 3) * 4 + (bidx & 3);
  const int by  = (xcd >> 2) * 8 + (bidx >> 2);
  const int m0 = bx * 256;
  const int w0 = by * 256;             // W' row base

  // staging: thread loads 16B; LDS dest lane-contiguous (global_load_lds rule),
  // XOR swizzle applied to the global source chunk index.
  const int srow   = tid >> 3;                       // 0..63 (row within round)
  const int schunk = ((tid & 7) ^ (srow & 7)) << 3;  // swizzled chunk * 8 hw

  const int col  = lane & 15;
  const int quad = lane >> 4;

  const unsigned short* Asrc = A + (size_t)(m0 + srow) * K2 + schunk;
  const unsigned short* Wsrc = W + (size_t)(w0 + srow) * K2 + schunk;
  const int ldsdst = wave * 512;       // shorts

  f32x4 acc[8][4];
#pragma unroll
  for (int i = 0; i < 8; ++i)
#pragma unroll
    for (int j = 0; j < 4; ++j)
      acc[i][j] = (f32x4){0.f, 0.f, 0.f, 0.f};

  auto stA = [&](int kt, int buf, int p) {
    gload_lds16(Asrc + (size_t)p * 64 * K2 + kt * 64,
                &lds[buf * 32768 + p * 4096 + ldsdst]);
  };
  auto stB = [&](int kt, int buf, int p) {
    gload_lds16(Wsrc + (size_t)p * 64 * K2 + kt * 64,
                &lds[buf * 32768 + 16384 + p * 4096 + ldsdst]);
  };

  // read-side byte addressing: row R at R*128 B, chunk' = chunk ^ (R&7);
  // R&7 == col&7 for all fragment rows (bases are multiples of 16).
  const unsigned lds0 = (unsigned)(size_t)(__attribute__((address_space(3))) char*)lds;
  const unsigned abase = lds0 + (unsigned)((wm * 128 + col) * 128);
  const unsigned bbase = lds0 + 32768u + (unsigned)((wn * 64 + col) * 128);
  const unsigned kch0 = ((quad ^ (col & 7)) << 4);        // ks=0 byte offset
  const unsigned kch1 = (((4 + quad) ^ (col & 7)) << 4);  // ks=1 byte offset

  // ---- prologue: stage tiles 0 (buf0) and 1 (buf1); publish tile 0 ---------
#pragma unroll
  for (int p = 0; p < 4; ++p) stA(0, 0, p);
#pragma unroll
  for (int p = 0; p < 4; ++p) stB(0, 0, p);
#pragma unroll
  for (int p = 0; p < 4; ++p) stA(1, 1, p);
#pragma unroll
  for (int p = 0; p < 4; ++p) stB(1, 1, p);
  asm volatile("s_waitcnt vmcnt(8)" ::: "memory");   // tile0 landed; tile1 in flight
  __builtin_amdgcn_sched_barrier(0);
  __builtin_amdgcn_s_barrier();

  bf16x8 bfrA[4][2], bfrB[4][2];
  // B frags of tile 0 (buf0, bo=0)
#pragma unroll
  for (int j = 0; j < 4; ++j) {
    bfrA[j][0] = dsr_b128(bbase + j * 2048 + kch0);
    bfrA[j][1] = dsr_b128(bbase + j * 2048 + kch1);
  }

  auto tile = [&](int kt, bf16x8 (&bcur)[4][2], bf16x8 (&bnxt)[4][2]) {
    const int buf = kt & 1;
    const unsigned bo  = (unsigned)(buf * 65536);
    const unsigned bon = bo ^ 65536u;
    bf16x8 af0[2][2], af1[2][2];
    RD_A(af0, 0, bo);
    RD_A(af1, 1, bo);
    LGKM(4);                        // bcur(8)+af0(4) retired; af1 in flight
    MFMA_PH(0, af0, bcur);
    RD_A(af0, 2, bo);
    LGKM(4);                        // af1 retired; ph2 in flight
    MFMA_PH(1, af1, bcur);
    RD_A(af1, 3, bo);
    LGKM(4);                        // ph2 retired; ph3 in flight
    MFMA_PH(2, af0, bcur);
    LGKM(0);                        // all own reads of buf[cur] complete
    __builtin_amdgcn_s_barrier();   // (1) all waves done reading buf[cur]
    if (kt + 2 < 32) {
      stA(kt + 2, buf, 0); stA(kt + 2, buf, 1);
      stA(kt + 2, buf, 2); stA(kt + 2, buf, 3);
      stB(kt + 2, buf, 0); stB(kt + 2, buf, 1);
      stB(kt + 2, buf, 2); stB(kt + 2, buf, 3);
      asm volatile("s_waitcnt vmcnt(8)" ::: "memory");  // kt+1 landed (own)
    } else {
      asm volatile("s_waitcnt vmcnt(0)" ::: "memory");  // tail drain
    }
    __builtin_amdgcn_sched_barrier(0);
    __builtin_amdgcn_s_barrier();   // (2) tile kt+1 visible to all waves
    if (kt < 31) {                  // B frags of tile kt+1 (returns hide under MFMA3)
#pragma unroll
      for (int j = 0; j < 4; ++j) {
        bnxt[j][0] = dsr_b128(bbase + bon + j * 2048 + kch0);
        bnxt[j][1] = dsr_b128(bbase + bon + j * 2048 + kch1);
      }
    }
    __builtin_amdgcn_sched_barrier(0);  // keep MFMA3 below the B issue
    MFMA_PH(3, af1, bcur);
  };

  for (int kt = 0; kt < 32; kt += 2) {
    tile(kt,     bfrA, bfrB);
    tile(kt + 1, bfrB, bfrA);
  }

  // ---- fused LSTM epilogue ----
  // C/D layout: col = lane&15, row = quad*4 + r.  Gate g = N-fragment j.
  const int h = by * 64 + wn * 16 + col;
  const float bi  = bias_ih[h]         + bias_hh[h];
  const float bf_ = bias_ih[H + h]     + bias_hh[H + h];
  const float bc  = bias_ih[2 * H + h] + bias_hh[2 * H + h];
  const float bo_ = bias_ih[3 * H + h] + bias_hh[3 * H + h];
  const float di = Wpi[(size_t)h * (H + 1)];
  const float df = Wpf[(size_t)h * (H + 1)];
  const int mbase = m0 + wm * 128 + quad * 4;
#pragma unroll
  for (int i = 0; i < 8; ++i) {
#pragma unroll
    for (int r = 0; r < 4; ++r) {
      const int m = mbase + i * 16 + r;
      const float c  = cx[(size_t)m * H + h];
      const float ip = acc[i][0][r] + bi;
      const float fp = acc[i][1][r] + bf_;
      const float cp = acc[i][2][r] + bc;
      const float op = acc[i][3][r] + bo_;
      const float ig = sigm(ip + c * di);
      const float fg = sigm(fp + c * df);
      const float cg = tanh_fast(cp);
      const float cy = fg * c + ig * cg;
      const float og = sigm(op + cy * df);   // reference reuses W_peephole_f
      const float hy = og * tanh_fast(cy);
      out[(size_t)m * H + h] = hy;
      out[OUT_CY + (size_t)m * H + h] = cy;
    }
  }
}

extern "C" void kernel_launch(void* const* d_in, const int* in_sizes, int n_in,
                              void* d_out, int out_size, void* d_ws, size_t ws_size,
                              hipStream_t stream) {
  const float* x   = (const float*)d_in[0];
  const float* hx  = (const float*)d_in[1];
  const float* cx  = (const float*)d_in[2];
  const float* wih = (const float*)d_in[3];
  const float* whh = (const float*)d_in[4];
  const float* bih = (const float*)d_in[5];
  const float* bhh = (const float*)d_in[6];
  const float* wpi = (const float*)d_in[7];
  const float* wpf = (const float*)d_in[8];
  // d_in[9] (W_peephole_o) unused: reference reuses W_peephole_f for outgate.
  float* out = (float*)d_out;

  unsigned short* Abf = (unsigned short*)d_ws;
  unsigned short* Wbf = Abf + (size_t)BSZ * K2;

  cast_kernel<<<8192, 256, 0, stream>>>(x, hx, wih, whh, Abf, Wbf);

  dim3 grid(BSZ / 256, (4 * H) / 256);
  lstm_fused_gemm<<<grid, 512, 0, stream>>>(Abf, Wbf, cx, bih, bhh, wpi, wpf, out);
}

// Round 4
// 251.685 us; speedup vs baseline: 1.6095x; 1.6095x over previous
//
#include <hip/hip_runtime.h>
#include <cstdint>

// LSTM cell with (diagonal) peephole connections.
//   K1: cast x|hx -> bf16 A [4096][2048]; cast Wih|Whh -> bf16 W' [4096][2048]
//       with gate-interleaved row permutation np = (h>>4)*64 + g*16 + (h&15).
//   K2: 256x256 bf16 MFMA GEMM, 512 thr = 8 waves (2M x 4N), wave tile
//       128Mx64N acc[8][4], BK=64, double-buffered 128 KiB LDS.
//   Round-4 schedule: 2 barriers/tile, counted-lgkm pipelined reads, NO
//   cross-tile register state.
//     Round-2 (84us, MfmaUtil 33%): 9 barriers/tile lockstep -> LDS-return
//     burst then MFMA burst, serialized chip-wide; 6300 cyc/tile vs 2064
//     MFMA floor.
//     Round-3 (280us): same pipelining idea but cross-tile B-frag ping-pong
//     via by-reference lambda arrays -> rule #20 scratch spill (FETCH +190MB,
//     WRITE +30MB of pure scratch traffic, MfmaUtil 10%).
//   This round: per tile, all fragments are LOCAL (B 32 + A 2x16 VGPR,
//   literal indices only), read pipelining via in-order DS retirement:
//     issue B(8)+A0(4)+A1(4); lgkm(4) -> MFMA0        (A1 in flight)
//     issue A2; lgkm(4) -> MFMA1 | issue A3; lgkm(4) -> MFMA2
//     lgkm(0); BARRIER(1)   [all reads of buf[cur] complete in every wave]
//     stage kt+2 -> buf[cur] (8 gload_lds); vmcnt(8)  [kt+1 landed]
//     BARRIER(2)            [kt+1 visible]; MFMA3
//   Between barriers waves free-run: one wave's MFMA covers another's LDS
//   returns (no per-phase lockstep). Counted vmcnt(8) keeps kt+2's loads in
//   flight across both barriers (never vmcnt(0) mid-loop; drain at tail).
//   Staging safety: stage targets buf[cur] only after BARRIER(1), which
//   every wave reaches only after lgkm(0) = all its reads of buf[cur] done.
//   XCD-bijective remap (FETCH 83->59MB measured, keep). XOR swizzle
//   chunk' = chunk ^ (row&7) on the global source of global_load_lds and on
//   LDS reads: 0 bank conflicts (measured). ds_reads are inline asm
//   (invisible to alias analysis; ordering ours via barriers + counted lgkm +
//   sched_barrier(0), rule #18). Fused LSTM epilogue, lane-local.

namespace {

constexpr int H   = 1024;   // hidden
constexpr int K2  = 2048;   // I + H
constexpr int BSZ = 4096;   // batch (M)
constexpr size_t OUT_CY = (size_t)BSZ * H;

typedef __attribute__((ext_vector_type(8))) short bf16x8;
typedef __attribute__((ext_vector_type(4))) float f32x4;
typedef __attribute__((ext_vector_type(8))) unsigned short u16x8;

__device__ __forceinline__ unsigned short f2bf(float f) {
  union { float f; uint32_t u; } v; v.f = f;
  uint32_t u = v.u;
  u += 0x7FFFu + ((u >> 16) & 1u);   // round-to-nearest-even
  return (unsigned short)(u >> 16);
}

__device__ __forceinline__ float sigm(float x) {
  return 1.0f / (1.0f + __expf(-x));
}
__device__ __forceinline__ float tanh_fast(float x) {
  return 1.0f - 2.0f / (1.0f + __expf(2.0f * x));
}

__device__ __forceinline__ void gload_lds16(const void* g, void* l) {
  __builtin_amdgcn_global_load_lds(
      (const __attribute__((address_space(1))) void*)g,
      (__attribute__((address_space(3))) void*)l, 16, 0, 0);
}

// raw ds_read_b128 at LDS byte address; no memory operand -> no compiler
// aliasing ties to global_load_lds destinations. Ordering is explicit.
__device__ __forceinline__ bf16x8 dsr_b128(unsigned addr) {
  bf16x8 r;
  asm volatile("ds_read_b128 %0, %1" : "=v"(r) : "v"(addr));
  return r;
}

}  // namespace

// ---- K1: both casts in one launch -------------------------------------------
__global__ __launch_bounds__(256) void cast_kernel(
    const float* __restrict__ x, const float* __restrict__ hx,
    const float* __restrict__ wih, const float* __restrict__ whh,
    unsigned short* __restrict__ A, unsigned short* __restrict__ W) {
  int b = blockIdx.x;
  bool isW = b >= 4096;
  int t = (isW ? b - 4096 : b) * 256 + threadIdx.x;
  int idx = t * 8;
  int n = idx >> 11;
  int k = idx & 2047;
  const float* s0 = isW ? wih : x;
  const float* s1 = isW ? whh : hx;
  const float* src = (k < H) ? (s0 + (size_t)n * H + k)
                             : (s1 + (size_t)n * H + (k - H));
  float4 v0 = *(const float4*)src;
  float4 v1 = *(const float4*)(src + 4);
  u16x8 o;
  o[0] = f2bf(v0.x); o[1] = f2bf(v0.y); o[2] = f2bf(v0.z); o[3] = f2bf(v0.w);
  o[4] = f2bf(v1.x); o[5] = f2bf(v1.y); o[6] = f2bf(v1.z); o[7] = f2bf(v1.w);
  if (isW) {
    int g = n >> 10, hh = n & 1023;
    int np = ((hh >> 4) << 6) + (g << 4) + (hh & 15);   // 64-wide gate groups
    *(u16x8*)(W + (size_t)np * K2 + k) = o;
  } else {
    *(u16x8*)(A + (size_t)idx) = o;
  }
}

// macros used inside the tile body (static indices everywhere, rule #20)
#define RD_A(AF, Q, BO)                                            \
  AF[0][0] = dsr_b128(abase + (BO) + (2 * (Q) + 0) * 2048 + kch0); \
  AF[0][1] = dsr_b128(abase + (BO) + (2 * (Q) + 0) * 2048 + kch1); \
  AF[1][0] = dsr_b128(abase + (BO) + (2 * (Q) + 1) * 2048 + kch0); \
  AF[1][1] = dsr_b128(abase + (BO) + (2 * (Q) + 1) * 2048 + kch1);

#define MFMA_PH(Q, AF, BC)                                                   \
  __builtin_amdgcn_s_setprio(1);                                             \
  _Pragma("unroll") for (int i2 = 0; i2 < 2; ++i2)                           \
      _Pragma("unroll") for (int j = 0; j < 4; ++j)                          \
          acc[2 * (Q) + i2][j] = __builtin_amdgcn_mfma_f32_16x16x32_bf16(    \
              AF[i2][0], BC[j][0], acc[2 * (Q) + i2][j], 0, 0, 0);           \
  _Pragma("unroll") for (int i2 = 0; i2 < 2; ++i2)                           \
      _Pragma("unroll") for (int j = 0; j < 4; ++j)                          \
          acc[2 * (Q) + i2][j] = __builtin_amdgcn_mfma_f32_16x16x32_bf16(    \
              AF[i2][1], BC[j][1], acc[2 * (Q) + i2][j], 0, 0, 0);           \
  __builtin_amdgcn_s_setprio(0);

#define LGKM(N)                                           \
  asm volatile("s_waitcnt lgkmcnt(" #N ")" ::: "memory"); \
  __builtin_amdgcn_sched_barrier(0);

// One K-tile. BUF is a literal 0/1 at every expansion site.
#define TILE_BODY(KT, BUF)                                                   \
  {                                                                          \
    const unsigned bo = (BUF) * 65536u;                                      \
    bf16x8 bfr[4][2], af0[2][2], af1[2][2];                                  \
    _Pragma("unroll") for (int j = 0; j < 4; ++j) {                          \
      bfr[j][0] = dsr_b128(bbase + bo + j * 2048 + kch0);                    \
      bfr[j][1] = dsr_b128(bbase + bo + j * 2048 + kch1);                    \
    }                                                                        \
    RD_A(af0, 0, bo);                                                        \
    RD_A(af1, 1, bo);                                                        \
    LGKM(4);            /* B + af0 retired; af1 in flight */                 \
    MFMA_PH(0, af0, bfr);                                                    \
    RD_A(af0, 2, bo);                                                        \
    LGKM(4);            /* af1 retired; ph2 in flight */                     \
    MFMA_PH(1, af1, bfr);                                                    \
    RD_A(af1, 3, bo);                                                        \
    LGKM(4);            /* ph2 retired; ph3 in flight */                     \
    MFMA_PH(2, af0, bfr);                                                    \
    LGKM(0);            /* all own reads of buf[BUF] complete */             \
    __builtin_amdgcn_s_barrier(); /* (1) every wave done reading buf[BUF] */ \
    if ((KT) + 2 < 32) {                                                     \
      stA((KT) + 2, (BUF), 0); stA((KT) + 2, (BUF), 1);                      \
      stA((KT) + 2, (BUF), 2); stA((KT) + 2, (BUF), 3);                      \
      stB((KT) + 2, (BUF), 0); stB((KT) + 2, (BUF), 1);                      \
      stB((KT) + 2, (BUF), 2); stB((KT) + 2, (BUF), 3);                      \
      asm volatile("s_waitcnt vmcnt(8)" ::: "memory"); /* kt+1 landed */     \
    } else {                                                                 \
      asm volatile("s_waitcnt vmcnt(0)" ::: "memory"); /* tail drain */      \
    }                                                                        \
    __builtin_amdgcn_sched_barrier(0);                                       \
    __builtin_amdgcn_s_barrier(); /* (2) tile kt+1 visible to all waves */   \
    MFMA_PH(3, af1, bfr); /* overlaps next tile's read issues */             \
  }

// ---- K2: fused GEMM + LSTM epilogue -----------------------------------------
// grid = 256 blocks (16x16 logical), block = 512 (8 waves, 2M x 4N)
__global__ __launch_bounds__(512, 2) void lstm_fused_gemm(
    const unsigned short* __restrict__ A,   // [4096][2048] bf16
    const unsigned short* __restrict__ W,   // [4096][2048] bf16, permuted rows
    const float* __restrict__ cx,
    const float* __restrict__ bias_ih, const float* __restrict__ bias_hh,
    const float* __restrict__ Wpi, const float* __restrict__ Wpf,
    float* __restrict__ out) {
  // [buf][ A 256x64 | B 256x64 ] bf16 = 2 * 32768 shorts = 128 KiB
  __shared__ __align__(16) unsigned short lds[2 * 32768];

  const int tid  = threadIdx.x;
  const int lane = tid & 63;
  const int wave = tid >> 6;
  const int wm   = wave >> 2;          // 0..1: M half
  const int wn   = wave & 3;           // 0..3: N quarter

  // XCD-aware bijective remap: linear id b -> XCD b&7 -> 4bx x 8by patch.
  const int b   = blockIdx.y * 16 + blockIdx.x;
  const int xcd = b & 7, bidx = b >> 3;
  const int bx  = (xcd & 3) * 4 + (bidx & 3);
  const int by  = (xcd >> 2) * 8 + (bidx >> 2);
  const int m0 = bx * 256;
  const int w0 = by * 256;             // W' row base

  // staging: thread loads 16B; LDS dest lane-contiguous (global_load_lds rule),
  // XOR swizzle applied to the global source chunk index.
  const int srow   = tid >> 3;                       // 0..63 (row within round)
  const int schunk = ((tid & 7) ^ (srow & 7)) << 3;  // swizzled chunk * 8 hw

  const int col  = lane & 15;
  const int quad = lane >> 4;

  const unsigned short* Asrc = A + (size_t)(m0 + srow) * K2 + schunk;
  const unsigned short* Wsrc = W + (size_t)(w0 + srow) * K2 + schunk;
  const int ldsdst = wave * 512;       // shorts

  f32x4 acc[8][4];
#pragma unroll
  for (int i = 0; i < 8; ++i)
#pragma unroll
    for (int j = 0; j < 4; ++j)
      acc[i][j] = (f32x4){0.f, 0.f, 0.f, 0.f};

  auto stA = [&](int kt, int buf, int p) {
    gload_lds16(Asrc + (size_t)p * 64 * K2 + kt * 64,
                &lds[buf * 32768 + p * 4096 + ldsdst]);
  };
  auto stB = [&](int kt, int buf, int p) {
    gload_lds16(Wsrc + (size_t)p * 64 * K2 + kt * 64,
                &lds[buf * 32768 + 16384 + p * 4096 + ldsdst]);
  };

  // read-side byte addressing: row R at R*128 B, chunk' = chunk ^ (R&7);
  // R&7 == col&7 for all fragment rows (bases are multiples of 16).
  const unsigned lds0 = (unsigned)(size_t)(__attribute__((address_space(3))) char*)lds;
  const unsigned abase = lds0 + (unsigned)((wm * 128 + col) * 128);
  const unsigned bbase = lds0 + 32768u + (unsigned)((wn * 64 + col) * 128);
  const unsigned kch0 = ((quad ^ (col & 7)) << 4);        // ks=0 byte offset
  const unsigned kch1 = (((4 + quad) ^ (col & 7)) << 4);  // ks=1 byte offset

  // ---- prologue: stage tiles 0 (buf0) and 1 (buf1); publish tile 0 ---------
#pragma unroll
  for (int p = 0; p < 4; ++p) stA(0, 0, p);
#pragma unroll
  for (int p = 0; p < 4; ++p) stB(0, 0, p);
#pragma unroll
  for (int p = 0; p < 4; ++p) stA(1, 1, p);
#pragma unroll
  for (int p = 0; p < 4; ++p) stB(1, 1, p);
  asm volatile("s_waitcnt vmcnt(8)" ::: "memory");   // tile0 landed; tile1 in flight
  __builtin_amdgcn_sched_barrier(0);
  __builtin_amdgcn_s_barrier();

  for (int kt = 0; kt < 32; kt += 2) {
    TILE_BODY(kt, 0);
    TILE_BODY(kt + 1, 1);
  }

  // ---- fused LSTM epilogue ----
  // C/D layout: col = lane&15, row = quad*4 + r.  Gate g = N-fragment j.
  const int h = by * 64 + wn * 16 + col;
  const float bi  = bias_ih[h]         + bias_hh[h];
  const float bf_ = bias_ih[H + h]     + bias_hh[H + h];
  const float bc  = bias_ih[2 * H + h] + bias_hh[2 * H + h];
  const float bo_ = bias_ih[3 * H + h] + bias_hh[3 * H + h];
  const float di = Wpi[(size_t)h * (H + 1)];
  const float df = Wpf[(size_t)h * (H + 1)];
  const int mbase = m0 + wm * 128 + quad * 4;
#pragma unroll
  for (int i = 0; i < 8; ++i) {
#pragma unroll
    for (int r = 0; r < 4; ++r) {
      const int m = mbase + i * 16 + r;
      const float c  = cx[(size_t)m * H + h];
      const float ip = acc[i][0][r] + bi;
      const float fp = acc[i][1][r] + bf_;
      const float cp = acc[i][2][r] + bc;
      const float op = acc[i][3][r] + bo_;
      const float ig = sigm(ip + c * di);
      const float fg = sigm(fp + c * df);
      const float cg = tanh_fast(cp);
      const float cy = fg * c + ig * cg;
      const float og = sigm(op + cy * df);   // reference reuses W_peephole_f
      const float hy = og * tanh_fast(cy);
      out[(size_t)m * H + h] = hy;
      out[OUT_CY + (size_t)m * H + h] = cy;
    }
  }
}

extern "C" void kernel_launch(void* const* d_in, const int* in_sizes, int n_in,
                              void* d_out, int out_size, void* d_ws, size_t ws_size,
                              hipStream_t stream) {
  const float* x   = (const float*)d_in[0];
  const float* hx  = (const float*)d_in[1];
  const float* cx  = (const float*)d_in[2];
  const float* wih = (const float*)d_in[3];
  const float* whh = (const float*)d_in[4];
  const float* bih = (const float*)d_in[5];
  const float* bhh = (const float*)d_in[6];
  const float* wpi = (const float*)d_in[7];
  const float* wpf = (const float*)d_in[8];
  // d_in[9] (W_peephole_o) unused: reference reuses W_peephole_f for outgate.
  float* out = (float*)d_out;

  unsigned short* Abf = (unsigned short*)d_ws;
  unsigned short* Wbf = Abf + (size_t)BSZ * K2;

  cast_kernel<<<8192, 256, 0, stream>>>(x, hx, wih, whh, Abf, Wbf);

  dim3 grid(BSZ / 256, (4 * H) / 256);
  lstm_fused_gemm<<<grid, 512, 0, stream>>>(Abf, Wbf, cx, bih, bhh, wpi, wpf, out);
}

// Round 5
// 247.236 us; speedup vs baseline: 1.6385x; 1.0180x over previous
//
#include <hip/hip_runtime.h>
#include <cstdint>

// LSTM cell with (diagonal) peephole connections.
//   K1: cast x|hx -> bf16 A [4096][2048]; cast Wih|Whh -> bf16 W' [4096][2048]
//       with gate-interleaved row permutation np = (h>>4)*64 + g*16 + (h&15).
//   K2: 256x256 bf16 MFMA GEMM, 512 thr = 8 waves (2M x 4N), wave tile
//       128Mx64N acc[8][4], BK=64, double-buffered 128 KiB LDS.
//   Round-5 schedule: 2 barriers/tile, counted-lgkm pipelined reads, ALL
//   fragment lifetimes end before barrier(1).
//     Round-2 (84us GEMM, MfmaUtil 33%): 9 barriers/tile lockstep -- LDS
//       return burst then MFMA burst, serialized; 6300 cyc/tile vs 2060 floor.
//     Round-3 (280us): cross-tile by-reference frag ping-pong -> rule #20
//       scratch (FETCH +190MB).
//     Round-4 (129us): 2-barrier pipeline but MFMA_PH(3) AFTER barrier(2) ->
//       bfr+af1 (48 regs) live across staging+barriers; 512thr @ 128KiB LDS
//       = 1 block/CU = 2 waves/SIMD = 256-reg cap; acc(128)+frags+staging
//       temps crossed it -> WRITE_SIZE +16MB scratch, MfmaUtil 21%.
//   This round, per tile (all frags local, literal indices, dead by barrier):
//     issue B(8)+A0(4)+A1(4); lgkm(4) -> MFMA0 ; issue A2
//     lgkm(4) -> MFMA1 ; issue A3 | lgkm(4) -> MFMA2 | lgkm(0) -> MFMA3
//     BARRIER(1)  [every wave's reads of buf[cur] complete]
//     stage kt+2 -> buf[cur] (8 gload_lds); vmcnt(8) [kt+1 landed]
//     BARRIER(2)  [kt+1 visible to all waves]
//   In-order DS retirement makes the lgkm counts exact; each MFMA cluster
//   (~256 SIMD-cyc) covers the next subtile's LDS return (~140 cyc).
//   Counted vmcnt(8) keeps kt+2's loads in flight across both barriers
//   (never vmcnt(0) mid-loop; drain at kt=30/31 tail).
//   Staging safety: stage targets buf[cur] only after BARRIER(1), reached
//   only after each wave's lgkm(0) = all its reads of buf[cur] done.
//   XCD-bijective remap (FETCH 83->59MB measured, keep). XOR swizzle
//   chunk' = chunk ^ (row&7) on the global source of global_load_lds and on
//   LDS reads: 0 bank conflicts (measured). ds_reads are inline asm
//   (invisible to alias analysis; ordering ours via barriers + counted lgkm +
//   sched_barrier(0), rule #18). Fused LSTM epilogue, lane-local.

namespace {

constexpr int H   = 1024;   // hidden
constexpr int K2  = 2048;   // I + H
constexpr int BSZ = 4096;   // batch (M)
constexpr size_t OUT_CY = (size_t)BSZ * H;

typedef __attribute__((ext_vector_type(8))) short bf16x8;
typedef __attribute__((ext_vector_type(4))) float f32x4;
typedef __attribute__((ext_vector_type(8))) unsigned short u16x8;

__device__ __forceinline__ unsigned short f2bf(float f) {
  union { float f; uint32_t u; } v; v.f = f;
  uint32_t u = v.u;
  u += 0x7FFFu + ((u >> 16) & 1u);   // round-to-nearest-even
  return (unsigned short)(u >> 16);
}

__device__ __forceinline__ float sigm(float x) {
  return 1.0f / (1.0f + __expf(-x));
}
__device__ __forceinline__ float tanh_fast(float x) {
  return 1.0f - 2.0f / (1.0f + __expf(2.0f * x));
}

__device__ __forceinline__ void gload_lds16(const void* g, void* l) {
  __builtin_amdgcn_global_load_lds(
      (const __attribute__((address_space(1))) void*)g,
      (__attribute__((address_space(3))) void*)l, 16, 0, 0);
}

// raw ds_read_b128 at LDS byte address; no memory operand -> no compiler
// aliasing ties to global_load_lds destinations. Ordering is explicit.
__device__ __forceinline__ bf16x8 dsr_b128(unsigned addr) {
  bf16x8 r;
  asm volatile("ds_read_b128 %0, %1" : "=v"(r) : "v"(addr));
  return r;
}

}  // namespace

// ---- K1: both casts in one launch -------------------------------------------
__global__ __launch_bounds__(256) void cast_kernel(
    const float* __restrict__ x, const float* __restrict__ hx,
    const float* __restrict__ wih, const float* __restrict__ whh,
    unsigned short* __restrict__ A, unsigned short* __restrict__ W) {
  int b = blockIdx.x;
  bool isW = b >= 4096;
  int t = (isW ? b - 4096 : b) * 256 + threadIdx.x;
  int idx = t * 8;
  int n = idx >> 11;
  int k = idx & 2047;
  const float* s0 = isW ? wih : x;
  const float* s1 = isW ? whh : hx;
  const float* src = (k < H) ? (s0 + (size_t)n * H + k)
                             : (s1 + (size_t)n * H + (k - H));
  float4 v0 = *(const float4*)src;
  float4 v1 = *(const float4*)(src + 4);
  u16x8 o;
  o[0] = f2bf(v0.x); o[1] = f2bf(v0.y); o[2] = f2bf(v0.z); o[3] = f2bf(v0.w);
  o[4] = f2bf(v1.x); o[5] = f2bf(v1.y); o[6] = f2bf(v1.z); o[7] = f2bf(v1.w);
  if (isW) {
    int g = n >> 10, hh = n & 1023;
    int np = ((hh >> 4) << 6) + (g << 4) + (hh & 15);   // 64-wide gate groups
    *(u16x8*)(W + (size_t)np * K2 + k) = o;
  } else {
    *(u16x8*)(A + (size_t)idx) = o;
  }
}

// macros used inside the tile body (static indices everywhere, rule #20)
#define RD_A(AF, Q, BO)                                            \
  AF[0][0] = dsr_b128(abase + (BO) + (2 * (Q) + 0) * 2048 + kch0); \
  AF[0][1] = dsr_b128(abase + (BO) + (2 * (Q) + 0) * 2048 + kch1); \
  AF[1][0] = dsr_b128(abase + (BO) + (2 * (Q) + 1) * 2048 + kch0); \
  AF[1][1] = dsr_b128(abase + (BO) + (2 * (Q) + 1) * 2048 + kch1);

#define MFMA_PH(Q, AF, BC)                                                   \
  __builtin_amdgcn_s_setprio(1);                                             \
  _Pragma("unroll") for (int i2 = 0; i2 < 2; ++i2)                           \
      _Pragma("unroll") for (int j = 0; j < 4; ++j)                          \
          acc[2 * (Q) + i2][j] = __builtin_amdgcn_mfma_f32_16x16x32_bf16(    \
              AF[i2][0], BC[j][0], acc[2 * (Q) + i2][j], 0, 0, 0);           \
  _Pragma("unroll") for (int i2 = 0; i2 < 2; ++i2)                           \
      _Pragma("unroll") for (int j = 0; j < 4; ++j)                          \
          acc[2 * (Q) + i2][j] = __builtin_amdgcn_mfma_f32_16x16x32_bf16(    \
              AF[i2][1], BC[j][1], acc[2 * (Q) + i2][j], 0, 0, 0);           \
  __builtin_amdgcn_s_setprio(0);

#define LGKM(N)                                           \
  asm volatile("s_waitcnt lgkmcnt(" #N ")" ::: "memory"); \
  __builtin_amdgcn_sched_barrier(0);

// One K-tile. BUF is a literal 0/1 at every expansion site.
// All fragments dead before BARRIER(1): nothing lives across staging.
#define TILE_BODY(KT, BUF)                                                   \
  {                                                                          \
    const unsigned bo = (BUF) * 65536u;                                      \
    bf16x8 bfr[4][2], af0[2][2], af1[2][2];                                  \
    _Pragma("unroll") for (int j = 0; j < 4; ++j) {                          \
      bfr[j][0] = dsr_b128(bbase + bo + j * 2048 + kch0);                    \
      bfr[j][1] = dsr_b128(bbase + bo + j * 2048 + kch1);                    \
    }                                                                        \
    RD_A(af0, 0, bo);                                                        \
    RD_A(af1, 1, bo);   /* 16 outstanding */                                 \
    LGKM(4);            /* B + af0 retired; af1 in flight */                 \
    MFMA_PH(0, af0, bfr);                                                    \
    RD_A(af0, 2, bo);                                                        \
    LGKM(4);            /* af1 retired; A2 in flight */                      \
    MFMA_PH(1, af1, bfr);                                                    \
    RD_A(af1, 3, bo);                                                        \
    LGKM(4);            /* A2 retired; A3 in flight */                       \
    MFMA_PH(2, af0, bfr);                                                    \
    LGKM(0);            /* A3 retired; all reads of buf[BUF] complete */     \
    MFMA_PH(3, af1, bfr);                                                    \
    __builtin_amdgcn_s_barrier(); /* (1) every wave done reading buf[BUF] */ \
    if ((KT) + 2 < 32) {                                                     \
      stA((KT) + 2, (BUF), 0); stA((KT) + 2, (BUF), 1);                      \
      stA((KT) + 2, (BUF), 2); stA((KT) + 2, (BUF), 3);                      \
      stB((KT) + 2, (BUF), 0); stB((KT) + 2, (BUF), 1);                      \
      stB((KT) + 2, (BUF), 2); stB((KT) + 2, (BUF), 3);                      \
      asm volatile("s_waitcnt vmcnt(8)" ::: "memory"); /* kt+1 landed */     \
    } else {                                                                 \
      asm volatile("s_waitcnt vmcnt(0)" ::: "memory"); /* tail drain */      \
    }                                                                        \
    __builtin_amdgcn_sched_barrier(0);                                       \
    __builtin_amdgcn_s_barrier(); /* (2) tile kt+1 visible to all waves */   \
  }

// ---- K2: fused GEMM + LSTM epilogue -----------------------------------------
// grid = 256 blocks (16x16 logical), block = 512 (8 waves, 2M x 4N)
__global__ __launch_bounds__(512, 2) void lstm_fused_gemm(
    const unsigned short* __restrict__ A,   // [4096][2048] bf16
    const unsigned short* __restrict__ W,   // [4096][2048] bf16, permuted rows
    const float* __restrict__ cx,
    const float* __restrict__ bias_ih, const float* __restrict__ bias_hh,
    const float* __restrict__ Wpi, const float* __restrict__ Wpf,
    float* __restrict__ out) {
  // [buf][ A 256x64 | B 256x64 ] bf16 = 2 * 32768 shorts = 128 KiB
  __shared__ __align__(16) unsigned short lds[2 * 32768];

  const int tid  = threadIdx.x;
  const int lane = tid & 63;
  const int wave = tid >> 6;
  const int wm   = wave >> 2;          // 0..1: M half
  const int wn   = wave & 3;           // 0..3: N quarter

  // XCD-aware bijective remap: linear id b -> XCD b&7 -> 4bx x 8by patch.
  const int b   = blockIdx.y * 16 + blockIdx.x;
  const int xcd = b & 7, bidx = b >> 3;
  const int bx  = (xcd & 3) * 4 + (bidx & 3);
  const int by  = (xcd >> 2) * 8 + (bidx >> 2);
  const int m0 = bx * 256;
  const int w0 = by * 256;             // W' row base

  // staging: thread loads 16B; LDS dest lane-contiguous (global_load_lds rule),
  // XOR swizzle applied to the global source chunk index.
  const int srow   = tid >> 3;                       // 0..63 (row within round)
  const int schunk = ((tid & 7) ^ (srow & 7)) << 3;  // swizzled chunk * 8 hw

  const int col  = lane & 15;
  const int quad = lane >> 4;

  const unsigned short* Asrc = A + (size_t)(m0 + srow) * K2 + schunk;
  const unsigned short* Wsrc = W + (size_t)(w0 + srow) * K2 + schunk;
  const int ldsdst = wave * 512;       // shorts

  f32x4 acc[8][4];
#pragma unroll
  for (int i = 0; i < 8; ++i)
#pragma unroll
    for (int j = 0; j < 4; ++j)
      acc[i][j] = (f32x4){0.f, 0.f, 0.f, 0.f};

  auto stA = [&](int kt, int buf, int p) {
    gload_lds16(Asrc + (size_t)p * 64 * K2 + kt * 64,
                &lds[buf * 32768 + p * 4096 + ldsdst]);
  };
  auto stB = [&](int kt, int buf, int p) {
    gload_lds16(Wsrc + (size_t)p * 64 * K2 + kt * 64,
                &lds[buf * 32768 + 16384 + p * 4096 + ldsdst]);
  };

  // read-side byte addressing: row R at R*128 B, chunk' = chunk ^ (R&7);
  // R&7 == col&7 for all fragment rows (bases are multiples of 16).
  const unsigned lds0 = (unsigned)(size_t)(__attribute__((address_space(3))) char*)lds;
  const unsigned abase = lds0 + (unsigned)((wm * 128 + col) * 128);
  const unsigned bbase = lds0 + 32768u + (unsigned)((wn * 64 + col) * 128);
  const unsigned kch0 = ((quad ^ (col & 7)) << 4);        // ks=0 byte offset
  const unsigned kch1 = (((4 + quad) ^ (col & 7)) << 4);  // ks=1 byte offset

  // ---- prologue: stage tiles 0 (buf0) and 1 (buf1); publish tile 0 ---------
#pragma unroll
  for (int p = 0; p < 4; ++p) stA(0, 0, p);
#pragma unroll
  for (int p = 0; p < 4; ++p) stB(0, 0, p);
#pragma unroll
  for (int p = 0; p < 4; ++p) stA(1, 1, p);
#pragma unroll
  for (int p = 0; p < 4; ++p) stB(1, 1, p);
  asm volatile("s_waitcnt vmcnt(8)" ::: "memory");   // tile0 landed; tile1 in flight
  __builtin_amdgcn_sched_barrier(0);
  __builtin_amdgcn_s_barrier();

  for (int kt = 0; kt < 32; kt += 2) {
    TILE_BODY(kt, 0);
    TILE_BODY(kt + 1, 1);
  }

  // ---- fused LSTM epilogue ----
  // C/D layout: col = lane&15, row = quad*4 + r.  Gate g = N-fragment j.
  const int h = by * 64 + wn * 16 + col;
  const float bi  = bias_ih[h]         + bias_hh[h];
  const float bf_ = bias_ih[H + h]     + bias_hh[H + h];
  const float bc  = bias_ih[2 * H + h] + bias_hh[2 * H + h];
  const float bo_ = bias_ih[3 * H + h] + bias_hh[3 * H + h];
  const float di = Wpi[(size_t)h * (H + 1)];
  const float df = Wpf[(size_t)h * (H + 1)];
  const int mbase = m0 + wm * 128 + quad * 4;
#pragma unroll
  for (int i = 0; i < 8; ++i) {
#pragma unroll
    for (int r = 0; r < 4; ++r) {
      const int m = mbase + i * 16 + r;
      const float c  = cx[(size_t)m * H + h];
      const float ip = acc[i][0][r] + bi;
      const float fp = acc[i][1][r] + bf_;
      const float cp = acc[i][2][r] + bc;
      const float op = acc[i][3][r] + bo_;
      const float ig = sigm(ip + c * di);
      const float fg = sigm(fp + c * df);
      const float cg = tanh_fast(cp);
      const float cy = fg * c + ig * cg;
      const float og = sigm(op + cy * df);   // reference reuses W_peephole_f
      const float hy = og * tanh_fast(cy);
      out[(size_t)m * H + h] = hy;
      out[OUT_CY + (size_t)m * H + h] = cy;
    }
  }
}

extern "C" void kernel_launch(void* const* d_in, const int* in_sizes, int n_in,
                              void* d_out, int out_size, void* d_ws, size_t ws_size,
                              hipStream_t stream) {
  const float* x   = (const float*)d_in[0];
  const float* hx  = (const float*)d_in[1];
  const float* cx  = (const float*)d_in[2];
  const float* wih = (const float*)d_in[3];
  const float* whh = (const float*)d_in[4];
  const float* bih = (const float*)d_in[5];
  const float* bhh = (const float*)d_in[6];
  const float* wpi = (const float*)d_in[7];
  const float* wpf = (const float*)d_in[8];
  // d_in[9] (W_peephole_o) unused: reference reuses W_peephole_f for outgate.
  float* out = (float*)d_out;

  unsigned short* Abf = (unsigned short*)d_ws;
  unsigned short* Wbf = Abf + (size_t)BSZ * K2;

  cast_kernel<<<8192, 256, 0, stream>>>(x, hx, wih, whh, Abf, Wbf);

  dim3 grid(BSZ / 256, (4 * H) / 256);
  lstm_fused_gemm<<<grid, 512, 0, stream>>>(Abf, Wbf, cx, bih, bhh, wpi, wpf, out);
}